// Round 3
// baseline (562.712 us; speedup 1.0000x reference)
//
#include <hip/hip_runtime.h>
#include <hip/hip_bf16.h>

typedef __bf16   bf16x8 __attribute__((ext_vector_type(8)));
typedef _Float16 f16x8  __attribute__((ext_vector_type(8)));
typedef float    f32x4  __attribute__((ext_vector_type(4)));

#define SCALE_QK 0.17677669529663687f   // 1/sqrt(32)
#define TL   136    // QmT/KmT transposed stride (halves): 272B rows, spreads banks

__device__ __forceinline__ float b2f(ushort u) {
    __hip_bfloat16 h; *reinterpret_cast<ushort*>(&h) = u; return __bfloat162float(h);
}
__device__ __forceinline__ ushort f2b(float f) {
    __hip_bfloat16 h = __float2bfloat16(f); return *reinterpret_cast<ushort*>(&h);
}
__device__ __forceinline__ ushort f2h(float f) {
    union { _Float16 h; ushort u; } x; x.h = (_Float16)f; return x.u;
}
__device__ __forceinline__ f16x8 cvt8f(float4 a, float4 b) {
    union { f16x8 v; ushort u[8]; } H;
    H.u[0] = f2h(a.x); H.u[1] = f2h(a.y); H.u[2] = f2h(a.z); H.u[3] = f2h(a.w);
    H.u[4] = f2h(b.x); H.u[5] = f2h(b.y); H.u[6] = f2h(b.z); H.u[7] = f2h(b.w);
    return H.v;
}

// ---------------------------------------------------------------------------
// K0: weight prep.
//  Wq,Wk,Wv (512x128) -> transposed f16 (128x512 each)
//  Wqo (128x512)      -> transposed bf16 (512x128)
//  Wo (128x512)       -> bf16 copy
// ---------------------------------------------------------------------------
__global__ void k_prep(const float* __restrict__ Wq, const float* __restrict__ Wk,
                       const float* __restrict__ Wv, const float* __restrict__ Wqo,
                       const float* __restrict__ Wo,
                       ushort* __restrict__ WqT, ushort* __restrict__ WkT,
                       ushort* __restrict__ WvT, ushort* __restrict__ WqoT,
                       ushort* __restrict__ WoB) {
    int idx = blockIdx.x * 256 + threadIdx.x;   // 5 * 65536 total
    int mat = idx >> 16, i = idx & 65535;
    if (mat == 0) {
        int n = i >> 9, k = i & 511;
        WqT[i] = f2h(Wq[k * 128 + n]);
    } else if (mat == 1) {
        int n = i >> 9, k = i & 511;
        WkT[i] = f2h(Wk[k * 128 + n]);
    } else if (mat == 2) {
        int n = i >> 9, k = i & 511;
        WvT[i] = f2h(Wv[k * 128 + n]);
    } else if (mat == 3) {
        int n = i >> 7, k = i & 127;
        WqoT[i] = f2b(Wqo[k * 512 + n]);
    } else if (mat == 4) {
        WoB[i] = f2b(Wo[i]);
    }
}

// ---------------------------------------------------------------------------
// K1: fused Q/K/V projection (f16 MFMA) + per-block partial scores.
// LDS-free GEMM loops: A/B fragments loaded directly from global (fully
// coalesced 64B-line pattern; weights L2-resident). No k-loop barriers —
// waves free-run; compiler pipelines the unrolled loop with counted vmcnt.
// LDS holds only the transposed QmT/KmT for the score phase.
// ---------------------------------------------------------------------------
__global__ __launch_bounds__(256) void k_qkv_scores(
        const float* __restrict__ Qin, const float* __restrict__ KVin,
        const ushort* __restrict__ WqT, const ushort* __restrict__ WkT,
        const ushort* __restrict__ WvT,
        const float* __restrict__ bq, const float* __restrict__ bk,
        const float* __restrict__ bv,
        ushort* __restrict__ QmB, ushort* __restrict__ VmB,
        float* __restrict__ partial) {
    __shared__ __align__(16) ushort lds[2 * 128 * TL];   // 69632 B
    ushort* P1 = lds;              // QmT f16 [128][TL]
    ushort* P2 = lds + 128 * TL;   // KmT f16 [128][TL]

    const int row0 = blockIdx.x * 128;
    const int tid  = threadIdx.x;
    const int wid  = tid >> 6, lane = tid & 63;
    const int wm = wid >> 1, wn = wid & 1;
    const int quad = lane >> 4, l16 = lane & 15;

    // ---------------- phase (a): Q projection ----------------
    {
        f32x4 acc[4][4] = {};
#pragma unroll 4
        for (int k0 = 0; k0 < 512; k0 += 32) {
            f16x8 aF[4];
#pragma unroll
            for (int i = 0; i < 4; ++i) {
                const float* p = Qin + (size_t)(row0 + wm * 64 + i * 16 + l16) * 512 + k0 + quad * 8;
                aF[i] = cvt8f(*(const float4*)p, *(const float4*)(p + 4));
            }
#pragma unroll
            for (int j = 0; j < 4; ++j) {
                f16x8 bF = *reinterpret_cast<const f16x8*>(
                    &WqT[(size_t)(wn * 64 + j * 16 + l16) * 512 + k0 + quad * 8]);
#pragma unroll
                for (int i = 0; i < 4; ++i)
                    acc[i][j] = __builtin_amdgcn_mfma_f32_16x16x32_f16(aF[i], bF, acc[i][j], 0, 0, 0);
            }
        }
        // epilogue: QmB (global bf16) + QmT f16 -> P1
#pragma unroll
        for (int j = 0; j < 4; ++j) {
            int col = wn * 64 + j * 16 + l16;
            float bqv = bq[col];
#pragma unroll
            for (int i = 0; i < 4; ++i)
#pragma unroll
                for (int r = 0; r < 4; ++r) {
                    int row = wm * 64 + i * 16 + quad * 4 + r;
                    float v = acc[i][j][r] + bqv;
                    QmB[(size_t)(row0 + row) * 128 + col] = f2b(v);
                    P1[col * TL + row] = f2h(v);
                }
        }
    }

    // ---------------- phase (b): K + V projection ----------------
    {
        f32x4 accK[4][4] = {};
        f32x4 accV[4][4] = {};
#pragma unroll 4
        for (int k0 = 0; k0 < 512; k0 += 32) {
            f16x8 aF[4];
#pragma unroll
            for (int i = 0; i < 4; ++i) {
                const float* p = KVin + (size_t)(row0 + wm * 64 + i * 16 + l16) * 512 + k0 + quad * 8;
                aF[i] = cvt8f(*(const float4*)p, *(const float4*)(p + 4));
            }
#pragma unroll
            for (int j = 0; j < 4; ++j) {
                f16x8 bK = *reinterpret_cast<const f16x8*>(
                    &WkT[(size_t)(wn * 64 + j * 16 + l16) * 512 + k0 + quad * 8]);
                f16x8 bV = *reinterpret_cast<const f16x8*>(
                    &WvT[(size_t)(wn * 64 + j * 16 + l16) * 512 + k0 + quad * 8]);
#pragma unroll
                for (int i = 0; i < 4; ++i) {
                    accK[i][j] = __builtin_amdgcn_mfma_f32_16x16x32_f16(aF[i], bK, accK[i][j], 0, 0, 0);
                    accV[i][j] = __builtin_amdgcn_mfma_f32_16x16x32_f16(aF[i], bV, accV[i][j], 0, 0, 0);
                }
            }
        }
#pragma unroll
        for (int j = 0; j < 4; ++j) {
            int col = wn * 64 + j * 16 + l16;
            float bkv = bk[col], bvv = bv[col];
#pragma unroll
            for (int i = 0; i < 4; ++i)
#pragma unroll
                for (int r = 0; r < 4; ++r) {
                    int row = wm * 64 + i * 16 + quad * 4 + r;
                    float vv = accV[i][j][r] + bvv;
                    VmB[(size_t)(row0 + row) * 128 + col] = f2b(vv);
                    P2[col * TL + row] = f2h(accK[i][j][r] + bkv);
                }
        }
    }
    __syncthreads();       // P1/P2 complete before cross-wave reads

    // ---------------- phase (c): partial scores, one head per wave ----------
    {
        const int h = wid;                 // 4 waves = 4 heads
        f32x4 s[2][2] = {};
#pragma unroll
        for (int ks = 0; ks < 4; ++ks) {   // contract l = 0..127 in 4 steps of 32
            f16x8 qa[2], kb[2];
#pragma unroll
            for (int dt = 0; dt < 2; ++dt)
                qa[dt] = *reinterpret_cast<const f16x8*>(
                    &P1[(h * 32 + dt * 16 + l16) * TL + ks * 32 + quad * 8]);
#pragma unroll
            for (int et = 0; et < 2; ++et)
                kb[et] = *reinterpret_cast<const f16x8*>(
                    &P2[(h * 32 + et * 16 + l16) * TL + ks * 32 + quad * 8]);
#pragma unroll
            for (int dt = 0; dt < 2; ++dt)
#pragma unroll
                for (int et = 0; et < 2; ++et)
                    s[dt][et] = __builtin_amdgcn_mfma_f32_16x16x32_f16(qa[dt], kb[et], s[dt][et], 0, 0, 0);
        }
        const int b = blockIdx.x >> 5, sp = blockIdx.x & 31;
        float* P = partial + (size_t)(sp * 64 + b * 4 + h) * 1024;
#pragma unroll
        for (int dt = 0; dt < 2; ++dt)
#pragma unroll
            for (int et = 0; et < 2; ++et)
#pragma unroll
                for (int r = 0; r < 4; ++r) {
                    int d = dt * 16 + quad * 4 + r, e = et * 16 + l16;
                    P[d * 32 + e] = s[dt][et][r];
                }
    }
}

// ---------------------------------------------------------------------------
// K2: fused partial-reduce + softmax + Wc build.
// Grid (64 bh, 4 mq): 256 blocks. Wave-parallel softmax (32 rows x 8 lanes);
// Wo slice pre-converted to f32 in LDS; attn row cached in 32 regs.
// ---------------------------------------------------------------------------
__global__ __launch_bounds__(256) void k_attn(
        const float* __restrict__ partial, const ushort* __restrict__ WoB,
        float* __restrict__ attnOut, ushort* __restrict__ WcT) {
    int bh = blockIdx.x; int b = bh >> 2, h = bh & 3;
    int mq = blockIdx.y;                 // m-quarter: cols mq*128..+128 of Wo
    __shared__ float aS[1024];
    __shared__ float wSf[32 * 128];
    int t = threadIdx.x;
    for (int i = t; i < 1024; i += 256) {
        float s = 0.f;
#pragma unroll
        for (int sp = 0; sp < 32; ++sp)
            s += partial[(size_t)(sp * 64 + bh) * 1024 + i];
        aS[i] = s * SCALE_QK;
    }
    for (int i = t; i < 4096; i += 256) {
        int r = i >> 7, c = i & 127;
        wSf[i] = b2f(WoB[(size_t)(h * 32 + r) * 512 + mq * 128 + c]);
    }
    __syncthreads();
    {   // softmax: 32 rows x 8 lanes, 4 elems/lane
        int row = t >> 3, sub = t & 7;
        float v[4];
#pragma unroll
        for (int z = 0; z < 4; ++z) v[z] = aS[row * 32 + sub * 4 + z];
        float m = fmaxf(fmaxf(v[0], v[1]), fmaxf(v[2], v[3]));
#pragma unroll
        for (int off = 1; off < 8; off <<= 1)
            m = fmaxf(m, __shfl_xor(m, off, 64));
        float pz[4], s = 0.f;
#pragma unroll
        for (int z = 0; z < 4; ++z) { pz[z] = __expf(v[z] - m); s += pz[z]; }
#pragma unroll
        for (int off = 1; off < 8; off <<= 1)
            s += __shfl_xor(s, off, 64);
        float inv = 1.f / s;
#pragma unroll
        for (int z = 0; z < 4; ++z) aS[row * 32 + sub * 4 + z] = pz[z] * inv;
    }
    __syncthreads();
    if (mq == 0)
        for (int i = t; i < 1024; i += 256)
            attnOut[(size_t)bh * 1024 + i] = aS[i];
    // WcT slice: thread (e = t&31, mg = t>>5) does 16 m values
    int e = t & 31, mg = t >> 5;
    float prow[32];
#pragma unroll
    for (int d = 0; d < 32; ++d) prow[d] = aS[d * 32 + e];
#pragma unroll 4
    for (int mi = 0; mi < 16; ++mi) {
        int ml = mg * 16 + mi;
        float acc = 0.f;
#pragma unroll
        for (int d = 0; d < 32; ++d)
            acc += prow[d] * wSf[d * 128 + ml];
        int m = mq * 128 + ml;
        WcT[((size_t)b * 512 + m) * 128 + h * 32 + e] = f2b(acc);
    }
}

// ---------------------------------------------------------------------------
// K3: fused output GEMM + LayerNorm — LDS-free GEMM.
// x = Vm @ Wc_b + Qm @ Wqo + (bo+bqo); y = LN(x)*gamma+beta -> d_out fp32.
// A/B fragments loaded directly from global (B panels are 256KB/batch,
// L2-resident across the 64 blocks of a batch). No k-loop barriers.
// ---------------------------------------------------------------------------
__global__ __launch_bounds__(256) void k_out_ln(
        const ushort* __restrict__ Vm, const ushort* __restrict__ Qm,
        const ushort* __restrict__ WcT, const ushort* __restrict__ WqoT,
        const float* __restrict__ bo, const float* __restrict__ bqo,
        const float* __restrict__ gamma, const float* __restrict__ beta,
        float* __restrict__ Y) {
    __shared__ float sumS[4][64], sumSS[4][64], muA[64], rsA[64];
    const int row0 = blockIdx.x * 64;
    const int b = row0 >> 12;
    const ushort* WcTb = WcT + (size_t)b * 512 * 128;
    const int tid = threadIdx.x;
    const int wid = tid >> 6, lane = tid & 63;
    const int quad = lane >> 4, l16 = lane & 15;

    f32x4 acc[4][8] = {};

    const ushort* Asrc[2] = { Vm, Qm };
    const ushort* Bsrc[2] = { WcTb, WqoT };
#pragma unroll
    for (int half = 0; half < 2; ++half) {
        const ushort* A = Asrc[half];
        const ushort* B = Bsrc[half];
#pragma unroll 2
        for (int ks = 0; ks < 4; ++ks) {
            int kk = ks * 32;
            bf16x8 aF[4];
#pragma unroll
            for (int i = 0; i < 4; ++i)
                aF[i] = *reinterpret_cast<const bf16x8*>(
                    &A[(size_t)(row0 + i * 16 + l16) * 128 + kk + quad * 8]);
#pragma unroll
            for (int j = 0; j < 8; ++j) {
                bf16x8 bF = *reinterpret_cast<const bf16x8*>(
                    &B[(size_t)(wid * 128 + j * 16 + l16) * 128 + kk + quad * 8]);
#pragma unroll
                for (int i = 0; i < 4; ++i)
                    acc[i][j] = __builtin_amdgcn_mfma_f32_16x16x32_bf16(aF[i], bF, acc[i][j], 0, 0, 0);
            }
        }
    }

    float bv[8];
#pragma unroll
    for (int j = 0; j < 8; ++j) {
        int ncol = wid * 128 + j * 16 + l16;
        bv[j] = bo[ncol] + bqo[ncol];
    }
    float sArr[4][4], ssArr[4][4];
#pragma unroll
    for (int i = 0; i < 4; ++i)
#pragma unroll
        for (int r = 0; r < 4; ++r) {
            float s = 0.f, ss = 0.f;
#pragma unroll
            for (int j = 0; j < 8; ++j) {
                float x = acc[i][j][r] + bv[j];
                s += x; ss += x * x;
            }
            sArr[i][r] = s; ssArr[i][r] = ss;
        }
#pragma unroll
    for (int off = 1; off < 16; off <<= 1)
#pragma unroll
        for (int i = 0; i < 4; ++i)
#pragma unroll
            for (int r = 0; r < 4; ++r) {
                sArr[i][r]  += __shfl_xor(sArr[i][r],  off, 64);
                ssArr[i][r] += __shfl_xor(ssArr[i][r], off, 64);
            }
    if (l16 == 0) {
#pragma unroll
        for (int i = 0; i < 4; ++i)
#pragma unroll
            for (int r = 0; r < 4; ++r) {
                int row = i * 16 + quad * 4 + r;
                sumS[wid][row]  = sArr[i][r];
                sumSS[wid][row] = ssArr[i][r];
            }
    }
    __syncthreads();
    if (tid < 64) {
        float s = sumS[0][tid] + sumS[1][tid] + sumS[2][tid] + sumS[3][tid];
        float ss = sumSS[0][tid] + sumSS[1][tid] + sumSS[2][tid] + sumSS[3][tid];
        float mu = s * (1.f / 512.f);
        float var = ss * (1.f / 512.f) - mu * mu;
        muA[tid] = mu;
        rsA[tid] = rsqrtf(var + 1e-5f);
    }
    __syncthreads();

    float gj[8], bj[8];
#pragma unroll
    for (int j = 0; j < 8; ++j) {
        int ncol = wid * 128 + j * 16 + l16;
        gj[j] = gamma[ncol]; bj[j] = beta[ncol];
    }
#pragma unroll
    for (int i = 0; i < 4; ++i)
#pragma unroll
        for (int r = 0; r < 4; ++r) {
            int row = i * 16 + quad * 4 + r;
            float mu = muA[row], rstd = rsA[row];
            size_t base = (size_t)(row0 + row) * 512 + wid * 128 + l16;
#pragma unroll
            for (int j = 0; j < 8; ++j) {
                float x = acc[i][j][r] + bv[j];
                Y[base + j * 16] = (x - mu) * rstd * gj[j] + bj[j];
            }
        }
}

// ---------------------------------------------------------------------------
extern "C" void kernel_launch(void* const* d_in, const int* in_sizes, int n_in,
                              void* d_out, int out_size, void* d_ws, size_t ws_size,
                              hipStream_t stream) {
    const float* Qin   = (const float*)d_in[0];
    const float* KVin  = (const float*)d_in[1];
    const float* Wq    = (const float*)d_in[2];
    const float* bq    = (const float*)d_in[3];
    const float* Wk    = (const float*)d_in[4];
    const float* bk    = (const float*)d_in[5];
    const float* Wv    = (const float*)d_in[6];
    const float* bv    = (const float*)d_in[7];
    const float* Wo    = (const float*)d_in[8];
    const float* bo    = (const float*)d_in[9];
    const float* Wqo   = (const float*)d_in[10];
    const float* bqo   = (const float*)d_in[11];
    const float* gamma = (const float*)d_in[12];
    const float* beta  = (const float*)d_in[13];
    float* out = (float*)d_out;           // [y (16*4096*512) | attn (16*4*32*32)]
    float* attnOut = out + 33554432;

    char* ws = (char*)d_ws;
    ushort* WqT  = (ushort*)(ws);                 // 131072
    ushort* WkT  = (ushort*)(ws + 131072);        // 131072
    ushort* WvT  = (ushort*)(ws + 262144);        // 131072
    ushort* WqoT = (ushort*)(ws + 393216);        // 131072
    ushort* WoB  = (ushort*)(ws + 524288);        // 131072
    ushort* QmB  = (ushort*)(ws + 655360);        // 16777216
    ushort* VmB  = (ushort*)(ws + 17432576);      // 16777216
    float*  part = (float*) (ws + 34209792);      // 8388608
    ushort* WcT  = (ushort*)(ws + 42598400);      // 2097152
    // total ws use: 44,695,552 bytes

    k_prep<<<1280, 256, 0, stream>>>(Wq, Wk, Wv, Wqo, Wo,
                                     WqT, WkT, WvT, WqoT, WoB);
    k_qkv_scores<<<512, 256, 0, stream>>>(Qin, KVin, WqT, WkT, WvT,
                                          bq, bk, bv, QmB, VmB, part);
    k_attn<<<dim3(64, 4), 256, 0, stream>>>(part, WoB, attnOut, WcT);
    k_out_ln<<<1024, 256, 0, stream>>>(VmB, QmB, WcT, WqoT, bo, bqo, gamma, beta, out);
}

// Round 4
// 436.550 us; speedup vs baseline: 1.2890x; 1.2890x over previous
//
#include <hip/hip_runtime.h>
#include <hip/hip_bf16.h>

typedef __bf16   bf16x8 __attribute__((ext_vector_type(8)));
typedef _Float16 f16x8  __attribute__((ext_vector_type(8)));
typedef float    f32x4  __attribute__((ext_vector_type(4)));

#define SCALE_QK 0.17677669529663687f   // 1/sqrt(32)
#define LDSS 40     // staging stride (halves): 80B rows -> 2-way bank aliasing (free)
#define RS   136    // k_scores2 row-major tile stride (halves), 272B rows, 16B-aligned

__device__ __forceinline__ float b2f(ushort u) {
    __hip_bfloat16 h; *reinterpret_cast<ushort*>(&h) = u; return __bfloat162float(h);
}
__device__ __forceinline__ ushort f2b(float f) {
    __hip_bfloat16 h = __float2bfloat16(f); return *reinterpret_cast<ushort*>(&h);
}
__device__ __forceinline__ ushort f2h(float f) {
    union { _Float16 h; ushort u; } x; x.h = (_Float16)f; return x.u;
}
__device__ __forceinline__ uint4 cvt8(float4 a, float4 b) {
    union { uint4 v; ushort u[8]; } H;
    H.u[0] = f2h(a.x); H.u[1] = f2h(a.y); H.u[2] = f2h(a.z); H.u[3] = f2h(a.w);
    H.u[4] = f2h(b.x); H.u[5] = f2h(b.y); H.u[6] = f2h(b.z); H.u[7] = f2h(b.w);
    return H.v;
}

// ---------------------------------------------------------------------------
// K0: weight prep.
//  Wq,Wk,Wv (512x128) -> transposed f16 (128x512 each)
//  Wqo (128x512)      -> transposed bf16 (512x128)
//  Wo (128x512)       -> bf16 copy
// ---------------------------------------------------------------------------
__global__ void k_prep(const float* __restrict__ Wq, const float* __restrict__ Wk,
                       const float* __restrict__ Wv, const float* __restrict__ Wqo,
                       const float* __restrict__ Wo,
                       ushort* __restrict__ WqT, ushort* __restrict__ WkT,
                       ushort* __restrict__ WvT, ushort* __restrict__ WqoT,
                       ushort* __restrict__ WoB) {
    int idx = blockIdx.x * 256 + threadIdx.x;   // 5 * 65536 total
    int mat = idx >> 16, i = idx & 65535;
    if (mat == 0) {
        int n = i >> 9, k = i & 511;
        WqT[i] = f2h(Wq[k * 128 + n]);
    } else if (mat == 1) {
        int n = i >> 9, k = i & 511;
        WkT[i] = f2h(Wk[k * 128 + n]);
    } else if (mat == 2) {
        int n = i >> 9, k = i & 511;
        WvT[i] = f2h(Wv[k * 128 + n]);
    } else if (mat == 3) {
        int n = i >> 7, k = i & 127;
        WqoT[i] = f2b(Wqo[k * 512 + n]);
    } else if (mat == 4) {
        WoB[i] = f2b(Wo[i]);
    }
}

// ---------------------------------------------------------------------------
// K1: fused Q/K/V projection (f16 MFMA), slim LDS (staging only, 30720 B ->
// 3 blocks/CU). T14 reg-staging: loads for step t+1 issued before the compute
// barrier of step t. Outputs: QmB (bf16, for out_ln), QmH/KmH (f16, for
// scores), VmB (bf16). Scores moved to k_scores2.
// ---------------------------------------------------------------------------
__global__ __launch_bounds__(256) void k_qkv(
        const float* __restrict__ Qin, const float* __restrict__ KVin,
        const ushort* __restrict__ WqT, const ushort* __restrict__ WkT,
        const ushort* __restrict__ WvT,
        const float* __restrict__ bq, const float* __restrict__ bk,
        const float* __restrict__ bv,
        ushort* __restrict__ QmB, ushort* __restrict__ QmH,
        ushort* __restrict__ KmH, ushort* __restrict__ VmB) {
    __shared__ __align__(16) ushort As [128 * LDSS];
    __shared__ __align__(16) ushort Bs0[128 * LDSS];
    __shared__ __align__(16) ushort Bs1[128 * LDSS];   // total 30720 B

    const int row0 = blockIdx.x * 128;
    const int tid  = threadIdx.x;
    const int wid  = tid >> 6, lane = tid & 63;
    const int wm = wid >> 1, wn = wid & 1;
    const int quad = lane >> 4, l16 = lane & 15;
    const int sr = tid >> 2;
    const int sc = (tid & 3) * 8;

    float4 aR0, aR1, aR2, aR3;     // A staging regs (fp32)
    uint4  bR0, bR1;               // B0 staging regs (f16)
    uint4  cR0, cR1;               // B1 staging regs (f16, phase b only)

    // ---------------- phase (a): Q projection ----------------
    {
        f32x4 acc[4][4] = {};
        {   // prologue issue k0 = 0
            const float* Ab = Qin + (size_t)(row0 + sr) * 512 + sc;
            aR0 = *(const float4*)Ab;
            aR1 = *(const float4*)(Ab + 4);
            aR2 = *(const float4*)(Ab + (size_t)64 * 512);
            aR3 = *(const float4*)(Ab + (size_t)64 * 512 + 4);
            bR0 = *(const uint4*)&WqT[(size_t)sr * 512 + sc];
            bR1 = *(const uint4*)&WqT[(size_t)(sr + 64) * 512 + sc];
        }
        for (int k0 = 0; k0 < 512; k0 += 32) {
            __syncthreads();
            *(uint4*)&As[sr * LDSS + sc]        = cvt8(aR0, aR1);
            *(uint4*)&As[(sr + 64) * LDSS + sc] = cvt8(aR2, aR3);
            *(uint4*)&Bs0[sr * LDSS + sc]        = bR0;
            *(uint4*)&Bs0[(sr + 64) * LDSS + sc] = bR1;
            if (k0 < 480) {   // issue t+1 (in flight across MFMA below)
                const float* Ab = Qin + (size_t)(row0 + sr) * 512 + k0 + 32 + sc;
                aR0 = *(const float4*)Ab;
                aR1 = *(const float4*)(Ab + 4);
                aR2 = *(const float4*)(Ab + (size_t)64 * 512);
                aR3 = *(const float4*)(Ab + (size_t)64 * 512 + 4);
                bR0 = *(const uint4*)&WqT[(size_t)sr * 512 + k0 + 32 + sc];
                bR1 = *(const uint4*)&WqT[(size_t)(sr + 64) * 512 + k0 + 32 + sc];
            }
            __syncthreads();
            f16x8 aF[4];
#pragma unroll
            for (int i = 0; i < 4; ++i)
                aF[i] = *reinterpret_cast<const f16x8*>(&As[(wm * 64 + i * 16 + l16) * LDSS + quad * 8]);
#pragma unroll
            for (int j = 0; j < 4; ++j) {
                f16x8 bF = *reinterpret_cast<const f16x8*>(&Bs0[(wn * 64 + j * 16 + l16) * LDSS + quad * 8]);
#pragma unroll
                for (int i = 0; i < 4; ++i)
                    acc[i][j] = __builtin_amdgcn_mfma_f32_16x16x32_f16(aF[i], bF, acc[i][j], 0, 0, 0);
            }
        }
        // issue phase-(b) k0=0 loads now — latency hides under the epilogue
        {
            const float* Ab = KVin + (size_t)(row0 + sr) * 512 + sc;
            aR0 = *(const float4*)Ab;
            aR1 = *(const float4*)(Ab + 4);
            aR2 = *(const float4*)(Ab + (size_t)64 * 512);
            aR3 = *(const float4*)(Ab + (size_t)64 * 512 + 4);
            bR0 = *(const uint4*)&WkT[(size_t)sr * 512 + sc];
            bR1 = *(const uint4*)&WkT[(size_t)(sr + 64) * 512 + sc];
            cR0 = *(const uint4*)&WvT[(size_t)sr * 512 + sc];
            cR1 = *(const uint4*)&WvT[(size_t)(sr + 64) * 512 + sc];
        }
        // epilogue: QmB (bf16) + QmH (f16), both global
#pragma unroll
        for (int j = 0; j < 4; ++j) {
            int col = wn * 64 + j * 16 + l16;
            float bqv = bq[col];
#pragma unroll
            for (int i = 0; i < 4; ++i)
#pragma unroll
                for (int r = 0; r < 4; ++r) {
                    int row = wm * 64 + i * 16 + quad * 4 + r;
                    float v = acc[i][j][r] + bqv;
                    QmB[(size_t)(row0 + row) * 128 + col] = f2b(v);
                    QmH[(size_t)(row0 + row) * 128 + col] = f2h(v);
                }
        }
    }

    // ---------------- phase (b): K + V projection ----------------
    {
        f32x4 accK[4][4] = {};
        f32x4 accV[4][4] = {};
        for (int k0 = 0; k0 < 512; k0 += 32) {
            __syncthreads();
            *(uint4*)&As[sr * LDSS + sc]        = cvt8(aR0, aR1);
            *(uint4*)&As[(sr + 64) * LDSS + sc] = cvt8(aR2, aR3);
            *(uint4*)&Bs0[sr * LDSS + sc]        = bR0;
            *(uint4*)&Bs0[(sr + 64) * LDSS + sc] = bR1;
            *(uint4*)&Bs1[sr * LDSS + sc]        = cR0;
            *(uint4*)&Bs1[(sr + 64) * LDSS + sc] = cR1;
            if (k0 < 480) {
                const float* Ab = KVin + (size_t)(row0 + sr) * 512 + k0 + 32 + sc;
                aR0 = *(const float4*)Ab;
                aR1 = *(const float4*)(Ab + 4);
                aR2 = *(const float4*)(Ab + (size_t)64 * 512);
                aR3 = *(const float4*)(Ab + (size_t)64 * 512 + 4);
                bR0 = *(const uint4*)&WkT[(size_t)sr * 512 + k0 + 32 + sc];
                bR1 = *(const uint4*)&WkT[(size_t)(sr + 64) * 512 + k0 + 32 + sc];
                cR0 = *(const uint4*)&WvT[(size_t)sr * 512 + k0 + 32 + sc];
                cR1 = *(const uint4*)&WvT[(size_t)(sr + 64) * 512 + k0 + 32 + sc];
            }
            __syncthreads();
            f16x8 aF[4];
#pragma unroll
            for (int i = 0; i < 4; ++i)
                aF[i] = *reinterpret_cast<const f16x8*>(&As[(wm * 64 + i * 16 + l16) * LDSS + quad * 8]);
#pragma unroll
            for (int j = 0; j < 4; ++j) {
                f16x8 bK = *reinterpret_cast<const f16x8*>(&Bs0[(wn * 64 + j * 16 + l16) * LDSS + quad * 8]);
                f16x8 bV = *reinterpret_cast<const f16x8*>(&Bs1[(wn * 64 + j * 16 + l16) * LDSS + quad * 8]);
#pragma unroll
                for (int i = 0; i < 4; ++i) {
                    accK[i][j] = __builtin_amdgcn_mfma_f32_16x16x32_f16(aF[i], bK, accK[i][j], 0, 0, 0);
                    accV[i][j] = __builtin_amdgcn_mfma_f32_16x16x32_f16(aF[i], bV, accV[i][j], 0, 0, 0);
                }
            }
        }
        // epilogue: KmH (f16) + VmB (bf16), both global
#pragma unroll
        for (int j = 0; j < 4; ++j) {
            int col = wn * 64 + j * 16 + l16;
            float bkv = bk[col], bvv = bv[col];
#pragma unroll
            for (int i = 0; i < 4; ++i)
#pragma unroll
                for (int r = 0; r < 4; ++r) {
                    int row = wm * 64 + i * 16 + quad * 4 + r;
                    KmH[(size_t)(row0 + row) * 128 + col] = f2h(accK[i][j][r] + bkv);
                    VmB[(size_t)(row0 + row) * 128 + col] = f2b(accV[i][j][r] + bvv);
                }
        }
    }
}

// ---------------------------------------------------------------------------
// K1b: partial scores. One block per (b, sp); 4 waves = 4 heads.
// Stage QmH/KmH 128x128 tiles row-major in LDS (XOR-swizzled cols), then
// MFMA f16 contracting the row (sequence) dimension.
// partial[sp][b*4+h][d][e] = sum_{l in sp-chunk} Qm[l][h*32+d]*Km[l][h*32+e]
// ---------------------------------------------------------------------------
__global__ __launch_bounds__(256) void k_scores2(
        const ushort* __restrict__ QmH, const ushort* __restrict__ KmH,
        float* __restrict__ partial) {
    __shared__ __align__(16) ushort Qs[128 * RS];
    __shared__ __align__(16) ushort Ks[128 * RS];
    const int bs = blockIdx.x;
    const int b = bs >> 5, sp = bs & 31;
    const int t = threadIdx.x;
    const int wid = t >> 6, lane = t & 63;
    const int quad = lane >> 4, l16 = lane & 15;
    const size_t base = ((size_t)b * 4096 + sp * 128) * 128;

#pragma unroll
    for (int it = 0; it < 8; ++it) {
        int idx = it * 256 + t;
        int row = idx >> 4, c8 = (idx & 15) * 8;
        int swc = c8 ^ (((row >> 3) & 3) << 3);     // spread quads across banks
        *(uint4*)&Qs[row * RS + swc] = *(const uint4*)&QmH[base + (size_t)row * 128 + c8];
        *(uint4*)&Ks[row * RS + swc] = *(const uint4*)&KmH[base + (size_t)row * 128 + c8];
    }
    __syncthreads();

    const int h = wid;
    f32x4 s[2][2] = {};
#pragma unroll
    for (int ks = 0; ks < 4; ++ks) {       // contract l = 0..127 in 4 steps of 32
        f16x8 qa[2], kb[2];
#pragma unroll
        for (int dt = 0; dt < 2; ++dt) {
            union { f16x8 v; ushort u[8]; } Q, K;
#pragma unroll
            for (int z = 0; z < 8; ++z) {
                int row = ks * 32 + quad * 8 + z;
                int col = (h * 32 + dt * 16 + l16) ^ (((row >> 3) & 3) << 3);
                Q.u[z] = Qs[row * RS + col];
                K.u[z] = Ks[row * RS + col];
            }
            qa[dt] = Q.v; kb[dt] = K.v;
        }
#pragma unroll
        for (int dt = 0; dt < 2; ++dt)
#pragma unroll
            for (int et = 0; et < 2; ++et)
                s[dt][et] = __builtin_amdgcn_mfma_f32_16x16x32_f16(qa[dt], kb[et], s[dt][et], 0, 0, 0);
    }
    float* P = partial + (size_t)(sp * 64 + b * 4 + h) * 1024;
#pragma unroll
    for (int dt = 0; dt < 2; ++dt)
#pragma unroll
        for (int et = 0; et < 2; ++et)
#pragma unroll
            for (int r = 0; r < 4; ++r) {
                int d = dt * 16 + quad * 4 + r, e = et * 16 + l16;
                P[d * 32 + e] = s[dt][et][r];
            }
}

// ---------------------------------------------------------------------------
// K2: fused partial-reduce + softmax + Wc build.
// Grid (64 bh, 4 mq): 256 blocks. Wave-parallel softmax (32 rows x 8 lanes);
// Wo slice pre-converted to f32 in LDS; attn row cached in 32 regs.
// ---------------------------------------------------------------------------
__global__ __launch_bounds__(256) void k_attn(
        const float* __restrict__ partial, const ushort* __restrict__ WoB,
        float* __restrict__ attnOut, ushort* __restrict__ WcT) {
    int bh = blockIdx.x; int b = bh >> 2, h = bh & 3;
    int mq = blockIdx.y;                 // m-quarter: cols mq*128..+128 of Wo
    __shared__ float aS[1024];
    __shared__ float wSf[32 * 128];
    int t = threadIdx.x;
    for (int i = t; i < 1024; i += 256) {
        float s = 0.f;
#pragma unroll
        for (int sp = 0; sp < 32; ++sp)
            s += partial[(size_t)(sp * 64 + bh) * 1024 + i];
        aS[i] = s * SCALE_QK;
    }
    for (int i = t; i < 4096; i += 256) {
        int r = i >> 7, c = i & 127;
        wSf[i] = b2f(WoB[(size_t)(h * 32 + r) * 512 + mq * 128 + c]);
    }
    __syncthreads();
    {   // softmax: 32 rows x 8 lanes, 4 elems/lane
        int row = t >> 3, sub = t & 7;
        float v[4];
#pragma unroll
        for (int z = 0; z < 4; ++z) v[z] = aS[row * 32 + sub * 4 + z];
        float m = fmaxf(fmaxf(v[0], v[1]), fmaxf(v[2], v[3]));
#pragma unroll
        for (int off = 1; off < 8; off <<= 1)
            m = fmaxf(m, __shfl_xor(m, off, 64));
        float pz[4], s = 0.f;
#pragma unroll
        for (int z = 0; z < 4; ++z) { pz[z] = __expf(v[z] - m); s += pz[z]; }
#pragma unroll
        for (int off = 1; off < 8; off <<= 1)
            s += __shfl_xor(s, off, 64);
        float inv = 1.f / s;
#pragma unroll
        for (int z = 0; z < 4; ++z) aS[row * 32 + sub * 4 + z] = pz[z] * inv;
    }
    __syncthreads();
    if (mq == 0)
        for (int i = t; i < 1024; i += 256)
            attnOut[(size_t)bh * 1024 + i] = aS[i];
    // WcT slice: thread (e = t&31, mg = t>>5) does 16 m values
    int e = t & 31, mg = t >> 5;
    float prow[32];
#pragma unroll
    for (int d = 0; d < 32; ++d) prow[d] = aS[d * 32 + e];
#pragma unroll 4
    for (int mi = 0; mi < 16; ++mi) {
        int ml = mg * 16 + mi;
        float acc = 0.f;
#pragma unroll
        for (int d = 0; d < 32; ++d)
            acc += prow[d] * wSf[d * 128 + ml];
        int m = mq * 128 + ml;
        WcT[((size_t)b * 512 + m) * 128 + h * 32 + e] = f2b(acc);
    }
}

// ---------------------------------------------------------------------------
// K3: fused output GEMM + LayerNorm.  Block = 64 rows x 512 cols (full rows).
// x = Vm @ Wc_b + Qm @ Wqo + (bo+bqo); y = LN(x)*gamma+beta -> d_out fp32.
// (R0 structure — 2-barrier LDS staging; T14 variant regressed this kernel.)
// ---------------------------------------------------------------------------
__global__ __launch_bounds__(256) void k_out_ln(
        const ushort* __restrict__ Vm, const ushort* __restrict__ Qm,
        const ushort* __restrict__ WcT, const ushort* __restrict__ WqoT,
        const float* __restrict__ bo, const float* __restrict__ bqo,
        const float* __restrict__ gamma, const float* __restrict__ beta,
        float* __restrict__ Y) {
    __shared__ __align__(16) ushort As[64 * LDSS];
    __shared__ __align__(16) ushort Bs[512 * LDSS];
    __shared__ float sumS[4][64], sumSS[4][64], muA[64], rsA[64];
    const int row0 = blockIdx.x * 64;
    const int b = row0 >> 12;
    const ushort* WcTb = WcT + (size_t)b * 512 * 128;
    const int tid = threadIdx.x;
    const int wid = tid >> 6, lane = tid & 63;
    const int quad = lane >> 4, l16 = lane & 15;
    const int sr = tid >> 2;            // 0..63
    const int sc = (tid & 3) * 8;       // 0,8,16,24

    f32x4 acc[4][8] = {};

    for (int k0 = 0; k0 < 256; k0 += 32) {
        const ushort* Asrc; const ushort* Bsrc; int kk;
        if (k0 < 128) { Asrc = Vm; Bsrc = WcTb; kk = k0; }
        else          { Asrc = Qm; Bsrc = WqoT; kk = k0 - 128; }
        __syncthreads();
        *(uint4*)&As[sr * LDSS + sc] =
            *(const uint4*)&Asrc[(size_t)(row0 + sr) * 128 + kk + sc];
#pragma unroll
        for (int p = 0; p < 8; ++p) {
            int r = sr + p * 64;
            *(uint4*)&Bs[r * LDSS + sc] = *(const uint4*)&Bsrc[(size_t)r * 128 + kk + sc];
        }
        __syncthreads();
        bf16x8 aF[4];
#pragma unroll
        for (int i = 0; i < 4; ++i)
            aF[i] = *reinterpret_cast<const bf16x8*>(&As[(i * 16 + l16) * LDSS + quad * 8]);
#pragma unroll
        for (int j = 0; j < 8; ++j) {
            bf16x8 bF = *reinterpret_cast<const bf16x8*>(
                &Bs[(wid * 128 + j * 16 + l16) * LDSS + quad * 8]);
#pragma unroll
            for (int i = 0; i < 4; ++i)
                acc[i][j] = __builtin_amdgcn_mfma_f32_16x16x32_bf16(aF[i], bF, acc[i][j], 0, 0, 0);
        }
    }

    float bv[8];
#pragma unroll
    for (int j = 0; j < 8; ++j) {
        int ncol = wid * 128 + j * 16 + l16;
        bv[j] = bo[ncol] + bqo[ncol];
    }
    float sArr[4][4], ssArr[4][4];
#pragma unroll
    for (int i = 0; i < 4; ++i)
#pragma unroll
        for (int r = 0; r < 4; ++r) {
            float s = 0.f, ss = 0.f;
#pragma unroll
            for (int j = 0; j < 8; ++j) {
                float x = acc[i][j][r] + bv[j];
                s += x; ss += x * x;
            }
            sArr[i][r] = s; ssArr[i][r] = ss;
        }
#pragma unroll
    for (int off = 1; off < 16; off <<= 1)
#pragma unroll
        for (int i = 0; i < 4; ++i)
#pragma unroll
            for (int r = 0; r < 4; ++r) {
                sArr[i][r]  += __shfl_xor(sArr[i][r],  off, 64);
                ssArr[i][r] += __shfl_xor(ssArr[i][r], off, 64);
            }
    if (l16 == 0) {
#pragma unroll
        for (int i = 0; i < 4; ++i)
#pragma unroll
            for (int r = 0; r < 4; ++r) {
                int row = i * 16 + quad * 4 + r;
                sumS[wid][row]  = sArr[i][r];
                sumSS[wid][row] = ssArr[i][r];
            }
    }
    __syncthreads();
    if (tid < 64) {
        float s = sumS[0][tid] + sumS[1][tid] + sumS[2][tid] + sumS[3][tid];
        float ss = sumSS[0][tid] + sumSS[1][tid] + sumSS[2][tid] + sumSS[3][tid];
        float mu = s * (1.f / 512.f);
        float var = ss * (1.f / 512.f) - mu * mu;
        muA[tid] = mu;
        rsA[tid] = rsqrtf(var + 1e-5f);
    }
    __syncthreads();

    float gj[8], bj[8];
#pragma unroll
    for (int j = 0; j < 8; ++j) {
        int ncol = wid * 128 + j * 16 + l16;
        gj[j] = gamma[ncol]; bj[j] = beta[ncol];
    }
#pragma unroll
    for (int i = 0; i < 4; ++i)
#pragma unroll
        for (int r = 0; r < 4; ++r) {
            int row = i * 16 + quad * 4 + r;
            float mu = muA[row], rstd = rsA[row];
            size_t base = (size_t)(row0 + row) * 512 + wid * 128 + l16;
#pragma unroll
            for (int j = 0; j < 8; ++j) {
                float x = acc[i][j][r] + bv[j];
                Y[base + j * 16] = (x - mu) * rstd * gj[j] + bj[j];
            }
        }
}

// ---------------------------------------------------------------------------
extern "C" void kernel_launch(void* const* d_in, const int* in_sizes, int n_in,
                              void* d_out, int out_size, void* d_ws, size_t ws_size,
                              hipStream_t stream) {
    const float* Qin   = (const float*)d_in[0];
    const float* KVin  = (const float*)d_in[1];
    const float* Wq    = (const float*)d_in[2];
    const float* bq    = (const float*)d_in[3];
    const float* Wk    = (const float*)d_in[4];
    const float* bk    = (const float*)d_in[5];
    const float* Wv    = (const float*)d_in[6];
    const float* bv    = (const float*)d_in[7];
    const float* Wo    = (const float*)d_in[8];
    const float* bo    = (const float*)d_in[9];
    const float* Wqo   = (const float*)d_in[10];
    const float* bqo   = (const float*)d_in[11];
    const float* gamma = (const float*)d_in[12];
    const float* beta  = (const float*)d_in[13];
    float* out = (float*)d_out;           // [y (16*4096*512) | attn (16*4*32*32)]
    float* attnOut = out + 33554432;

    char* ws = (char*)d_ws;
    ushort* WqT  = (ushort*)(ws);                 // 131072
    ushort* WkT  = (ushort*)(ws + 131072);        // 131072
    ushort* WvT  = (ushort*)(ws + 262144);        // 131072
    ushort* WqoT = (ushort*)(ws + 393216);        // 131072
    ushort* WoB  = (ushort*)(ws + 524288);        // 131072
    ushort* QmB  = (ushort*)(ws + 655360);        // 16777216
    ushort* QmH  = (ushort*)(ws + 17432576);      // 16777216
    ushort* KmH  = (ushort*)(ws + 34209792);      // 16777216
    ushort* VmB  = (ushort*)(ws + 50987008);      // 16777216
    float*  part = (float*) (ws + 67764224);      // 8388608
    ushort* WcT  = (ushort*)(ws + 76152832);      // 2097152
    // total ws use: 78,249,984 bytes

    k_prep<<<1280, 256, 0, stream>>>(Wq, Wk, Wv, Wqo, Wo,
                                     WqT, WkT, WvT, WqoT, WoB);
    k_qkv<<<512, 256, 0, stream>>>(Qin, KVin, WqT, WkT, WvT,
                                   bq, bk, bv, QmB, QmH, KmH, VmB);
    k_scores2<<<512, 256, 0, stream>>>(QmH, KmH, part);
    k_attn<<<dim3(64, 4), 256, 0, stream>>>(part, WoB, attnOut, WcT);
    k_out_ln<<<1024, 256, 0, stream>>>(VmB, QmB, WcT, WqoT, bo, bqo, gamma, beta, out);
}

// Round 5
// 419.544 us; speedup vs baseline: 1.3412x; 1.0405x over previous
//
#include <hip/hip_runtime.h>
#include <hip/hip_bf16.h>

typedef __bf16   bf16x8 __attribute__((ext_vector_type(8)));
typedef _Float16 f16x8  __attribute__((ext_vector_type(8)));
typedef float    f32x4  __attribute__((ext_vector_type(4)));

#define SCALE_QK 0.17677669529663687f   // 1/sqrt(32)
#define LDSS 40     // staging stride (halves): 80B rows -> 2-way bank aliasing (free)
#define TL   136    // QmT/KmT transposed stride (halves): 272B rows, spreads banks

__device__ __forceinline__ float b2f(ushort u) {
    __hip_bfloat16 h; *reinterpret_cast<ushort*>(&h) = u; return __bfloat162float(h);
}
__device__ __forceinline__ ushort f2b(float f) {
    __hip_bfloat16 h = __float2bfloat16(f); return *reinterpret_cast<ushort*>(&h);
}
__device__ __forceinline__ ushort f2h(float f) {
    union { _Float16 h; ushort u; } x; x.h = (_Float16)f; return x.u;
}
__device__ __forceinline__ float h2f(ushort u) {
    union { _Float16 h; ushort u; } x; x.u = u; return (float)x.h;
}
__device__ __forceinline__ uint4 cvt8(float4 a, float4 b) {
    union { uint4 v; ushort u[8]; } H;
    H.u[0] = f2h(a.x); H.u[1] = f2h(a.y); H.u[2] = f2h(a.z); H.u[3] = f2h(a.w);
    H.u[4] = f2h(b.x); H.u[5] = f2h(b.y); H.u[6] = f2h(b.z); H.u[7] = f2h(b.w);
    return H.v;
}

// ---------------------------------------------------------------------------
// K0: weight prep.
//  Wq,Wk,Wv (512x128) -> transposed f16 (128x512 each)
//  Wqo (128x512)      -> transposed f16 (512x128)
//  Wo (128x512)       -> f16 copy
// ---------------------------------------------------------------------------
__global__ void k_prep(const float* __restrict__ Wq, const float* __restrict__ Wk,
                       const float* __restrict__ Wv, const float* __restrict__ Wqo,
                       const float* __restrict__ Wo,
                       ushort* __restrict__ WqT, ushort* __restrict__ WkT,
                       ushort* __restrict__ WvT, ushort* __restrict__ WqoT,
                       ushort* __restrict__ WoH) {
    int idx = blockIdx.x * 256 + threadIdx.x;   // 5 * 65536 total
    int mat = idx >> 16, i = idx & 65535;
    if (mat == 0) {
        int n = i >> 9, k = i & 511;
        WqT[i] = f2h(Wq[k * 128 + n]);
    } else if (mat == 1) {
        int n = i >> 9, k = i & 511;
        WkT[i] = f2h(Wk[k * 128 + n]);
    } else if (mat == 2) {
        int n = i >> 9, k = i & 511;
        WvT[i] = f2h(Wv[k * 128 + n]);
    } else if (mat == 3) {
        int n = i >> 7, k = i & 127;
        WqoT[i] = f2h(Wqo[k * 512 + n]);
    } else if (mat == 4) {
        WoH[i] = f2h(Wo[i]);
    }
}

// ---------------------------------------------------------------------------
// K1: fused Q/K/V projection (f16 MFMA) + per-block partial scores.
// T14 async-staged: loads for step t+1 issued before the compute barrier of
// step t (best-measured qkv config, R2 run). Staging LDS aliases the P2
// (KmT) score buffer; P1/P2 written only after their staging use ends.
// Outputs: QmH/VmH f16 (for out_ln), partial (fp32 scores).
// ---------------------------------------------------------------------------
__global__ __launch_bounds__(256) void k_qkv_scores(
        const float* __restrict__ Qin, const float* __restrict__ KVin,
        const ushort* __restrict__ WqT, const ushort* __restrict__ WkT,
        const ushort* __restrict__ WvT,
        const float* __restrict__ bq, const float* __restrict__ bk,
        const float* __restrict__ bv,
        ushort* __restrict__ QmH, ushort* __restrict__ VmH,
        float* __restrict__ partial) {
    __shared__ __align__(16) ushort lds[2 * 128 * TL];   // 69632 B
    ushort* P1  = lds;                    // QmT f16 [128][TL]
    ushort* P2  = lds + 128 * TL;         // KmT f16 [128][TL]; staging aliased here
    ushort* As  = P2;                     // 128*40 halves
    ushort* Bs0 = P2 + 128 * LDSS;
    ushort* Bs1 = P2 + 2 * 128 * LDSS;    // 3*128*40 = 15360 <= 17408 halves  OK

    const int row0 = blockIdx.x * 128;
    const int tid  = threadIdx.x;
    const int wid  = tid >> 6, lane = tid & 63;
    const int wm = wid >> 1, wn = wid & 1;
    const int quad = lane >> 4, l16 = lane & 15;
    const int sr = tid >> 2;
    const int sc = (tid & 3) * 8;

    float4 aR0, aR1, aR2, aR3;     // A staging regs (fp32)
    uint4  bR0, bR1;               // B0 staging regs (f16)
    uint4  cR0, cR1;               // B1 staging regs (f16, phase b only)

    // ---------------- phase (a): Q projection ----------------
    {
        f32x4 acc[4][4] = {};
        {   // prologue issue k0 = 0
            const float* Ab = Qin + (size_t)(row0 + sr) * 512 + sc;
            aR0 = *(const float4*)Ab;
            aR1 = *(const float4*)(Ab + 4);
            aR2 = *(const float4*)(Ab + (size_t)64 * 512);
            aR3 = *(const float4*)(Ab + (size_t)64 * 512 + 4);
            bR0 = *(const uint4*)&WqT[(size_t)sr * 512 + sc];
            bR1 = *(const uint4*)&WqT[(size_t)(sr + 64) * 512 + sc];
        }
        for (int k0 = 0; k0 < 512; k0 += 32) {
            __syncthreads();
            *(uint4*)&As[sr * LDSS + sc]        = cvt8(aR0, aR1);
            *(uint4*)&As[(sr + 64) * LDSS + sc] = cvt8(aR2, aR3);
            *(uint4*)&Bs0[sr * LDSS + sc]        = bR0;
            *(uint4*)&Bs0[(sr + 64) * LDSS + sc] = bR1;
            if (k0 < 480) {   // issue t+1 (in flight across MFMA below)
                const float* Ab = Qin + (size_t)(row0 + sr) * 512 + k0 + 32 + sc;
                aR0 = *(const float4*)Ab;
                aR1 = *(const float4*)(Ab + 4);
                aR2 = *(const float4*)(Ab + (size_t)64 * 512);
                aR3 = *(const float4*)(Ab + (size_t)64 * 512 + 4);
                bR0 = *(const uint4*)&WqT[(size_t)sr * 512 + k0 + 32 + sc];
                bR1 = *(const uint4*)&WqT[(size_t)(sr + 64) * 512 + k0 + 32 + sc];
            }
            __syncthreads();
            f16x8 aF[4];
#pragma unroll
            for (int i = 0; i < 4; ++i)
                aF[i] = *reinterpret_cast<const f16x8*>(&As[(wm * 64 + i * 16 + l16) * LDSS + quad * 8]);
#pragma unroll
            for (int j = 0; j < 4; ++j) {
                f16x8 bF = *reinterpret_cast<const f16x8*>(&Bs0[(wn * 64 + j * 16 + l16) * LDSS + quad * 8]);
#pragma unroll
                for (int i = 0; i < 4; ++i)
                    acc[i][j] = __builtin_amdgcn_mfma_f32_16x16x32_f16(aF[i], bF, acc[i][j], 0, 0, 0);
            }
        }
        // issue phase-(b) k0=0 loads now — latency hides under the epilogue
        {
            const float* Ab = KVin + (size_t)(row0 + sr) * 512 + sc;
            aR0 = *(const float4*)Ab;
            aR1 = *(const float4*)(Ab + 4);
            aR2 = *(const float4*)(Ab + (size_t)64 * 512);
            aR3 = *(const float4*)(Ab + (size_t)64 * 512 + 4);
            bR0 = *(const uint4*)&WkT[(size_t)sr * 512 + sc];
            bR1 = *(const uint4*)&WkT[(size_t)(sr + 64) * 512 + sc];
            cR0 = *(const uint4*)&WvT[(size_t)sr * 512 + sc];
            cR1 = *(const uint4*)&WvT[(size_t)(sr + 64) * 512 + sc];
        }
        // epilogue: QmH (f16, global) + QmT f16 -> P1 (P1 disjoint from staging)
#pragma unroll
        for (int j = 0; j < 4; ++j) {
            int col = wn * 64 + j * 16 + l16;
            float bqv = bq[col];
#pragma unroll
            for (int i = 0; i < 4; ++i)
#pragma unroll
                for (int r = 0; r < 4; ++r) {
                    int row = wm * 64 + i * 16 + quad * 4 + r;
                    float v = acc[i][j][r] + bqv;
                    ushort hv = f2h(v);
                    QmH[(size_t)(row0 + row) * 128 + col] = hv;
                    P1[col * TL + row] = hv;
                }
        }
    }

    // ---------------- phase (b): K + V projection ----------------
    {
        f32x4 accK[4][4] = {};
        f32x4 accV[4][4] = {};
        for (int k0 = 0; k0 < 512; k0 += 32) {
            __syncthreads();
            *(uint4*)&As[sr * LDSS + sc]        = cvt8(aR0, aR1);
            *(uint4*)&As[(sr + 64) * LDSS + sc] = cvt8(aR2, aR3);
            *(uint4*)&Bs0[sr * LDSS + sc]        = bR0;
            *(uint4*)&Bs0[(sr + 64) * LDSS + sc] = bR1;
            *(uint4*)&Bs1[sr * LDSS + sc]        = cR0;
            *(uint4*)&Bs1[(sr + 64) * LDSS + sc] = cR1;
            if (k0 < 480) {
                const float* Ab = KVin + (size_t)(row0 + sr) * 512 + k0 + 32 + sc;
                aR0 = *(const float4*)Ab;
                aR1 = *(const float4*)(Ab + 4);
                aR2 = *(const float4*)(Ab + (size_t)64 * 512);
                aR3 = *(const float4*)(Ab + (size_t)64 * 512 + 4);
                bR0 = *(const uint4*)&WkT[(size_t)sr * 512 + k0 + 32 + sc];
                bR1 = *(const uint4*)&WkT[(size_t)(sr + 64) * 512 + k0 + 32 + sc];
                cR0 = *(const uint4*)&WvT[(size_t)sr * 512 + k0 + 32 + sc];
                cR1 = *(const uint4*)&WvT[(size_t)(sr + 64) * 512 + k0 + 32 + sc];
            }
            __syncthreads();
            f16x8 aF[4];
#pragma unroll
            for (int i = 0; i < 4; ++i)
                aF[i] = *reinterpret_cast<const f16x8*>(&As[(wm * 64 + i * 16 + l16) * LDSS + quad * 8]);
#pragma unroll
            for (int j = 0; j < 4; ++j) {
                f16x8 bK = *reinterpret_cast<const f16x8*>(&Bs0[(wn * 64 + j * 16 + l16) * LDSS + quad * 8]);
                f16x8 bV = *reinterpret_cast<const f16x8*>(&Bs1[(wn * 64 + j * 16 + l16) * LDSS + quad * 8]);
#pragma unroll
                for (int i = 0; i < 4; ++i) {
                    accK[i][j] = __builtin_amdgcn_mfma_f32_16x16x32_f16(aF[i], bK, accK[i][j], 0, 0, 0);
                    accV[i][j] = __builtin_amdgcn_mfma_f32_16x16x32_f16(aF[i], bV, accV[i][j], 0, 0, 0);
                }
            }
        }
        __syncthreads();   // all staging reads done before overwriting P2 with KmT
#pragma unroll
        for (int j = 0; j < 4; ++j) {
            int col = wn * 64 + j * 16 + l16;
            float bkv = bk[col], bvv = bv[col];
#pragma unroll
            for (int i = 0; i < 4; ++i)
#pragma unroll
                for (int r = 0; r < 4; ++r) {
                    int row = wm * 64 + i * 16 + quad * 4 + r;
                    VmH[(size_t)(row0 + row) * 128 + col] = f2h(accV[i][j][r] + bvv);
                    P2[col * TL + row] = f2h(accK[i][j][r] + bkv);
                }
        }
    }
    __syncthreads();       // KmT complete before scores read it

    // ---------------- phase (c): partial scores, one head per wave ----------
    {
        const int h = wid;                 // 4 waves = 4 heads
        f32x4 s[2][2] = {};
#pragma unroll
        for (int ks = 0; ks < 4; ++ks) {   // contract l = 0..127 in 4 steps of 32
            f16x8 qa[2], kb[2];
#pragma unroll
            for (int dt = 0; dt < 2; ++dt)
                qa[dt] = *reinterpret_cast<const f16x8*>(
                    &P1[(h * 32 + dt * 16 + l16) * TL + ks * 32 + quad * 8]);
#pragma unroll
            for (int et = 0; et < 2; ++et)
                kb[et] = *reinterpret_cast<const f16x8*>(
                    &P2[(h * 32 + et * 16 + l16) * TL + ks * 32 + quad * 8]);
#pragma unroll
            for (int dt = 0; dt < 2; ++dt)
#pragma unroll
                for (int et = 0; et < 2; ++et)
                    s[dt][et] = __builtin_amdgcn_mfma_f32_16x16x32_f16(qa[dt], kb[et], s[dt][et], 0, 0, 0);
        }
        const int b = blockIdx.x >> 5, sp = blockIdx.x & 31;
        float* P = partial + (size_t)(sp * 64 + b * 4 + h) * 1024;
#pragma unroll
        for (int dt = 0; dt < 2; ++dt)
#pragma unroll
            for (int et = 0; et < 2; ++et)
#pragma unroll
                for (int r = 0; r < 4; ++r) {
                    int d = dt * 16 + quad * 4 + r, e = et * 16 + l16;
                    P[d * 32 + e] = s[dt][et][r];
                }
    }
}

// ---------------------------------------------------------------------------
// K2: fused partial-reduce + softmax + Wc build.
// Grid (64 bh, 4 mq): 256 blocks. Wave-parallel softmax (32 rows x 8 lanes);
// Wo slice pre-converted to f32 in LDS; attn row cached in 32 regs.
// ---------------------------------------------------------------------------
__global__ __launch_bounds__(256) void k_attn(
        const float* __restrict__ partial, const ushort* __restrict__ WoH,
        float* __restrict__ attnOut, ushort* __restrict__ WcT) {
    int bh = blockIdx.x; int b = bh >> 2, h = bh & 3;
    int mq = blockIdx.y;                 // m-quarter: cols mq*128..+128 of Wo
    __shared__ float aS[1024];
    __shared__ float wSf[32 * 128];
    int t = threadIdx.x;
    for (int i = t; i < 1024; i += 256) {
        float s = 0.f;
#pragma unroll
        for (int sp = 0; sp < 32; ++sp)
            s += partial[(size_t)(sp * 64 + bh) * 1024 + i];
        aS[i] = s * SCALE_QK;
    }
    for (int i = t; i < 4096; i += 256) {
        int r = i >> 7, c = i & 127;
        wSf[i] = h2f(WoH[(size_t)(h * 32 + r) * 512 + mq * 128 + c]);
    }
    __syncthreads();
    {   // softmax: 32 rows x 8 lanes, 4 elems/lane
        int row = t >> 3, sub = t & 7;
        float v[4];
#pragma unroll
        for (int z = 0; z < 4; ++z) v[z] = aS[row * 32 + sub * 4 + z];
        float m = fmaxf(fmaxf(v[0], v[1]), fmaxf(v[2], v[3]));
#pragma unroll
        for (int off = 1; off < 8; off <<= 1)
            m = fmaxf(m, __shfl_xor(m, off, 64));
        float pz[4], s = 0.f;
#pragma unroll
        for (int z = 0; z < 4; ++z) { pz[z] = __expf(v[z] - m); s += pz[z]; }
#pragma unroll
        for (int off = 1; off < 8; off <<= 1)
            s += __shfl_xor(s, off, 64);
        float inv = 1.f / s;
#pragma unroll
        for (int z = 0; z < 4; ++z) aS[row * 32 + sub * 4 + z] = pz[z] * inv;
    }
    __syncthreads();
    if (mq == 0)
        for (int i = t; i < 1024; i += 256)
            attnOut[(size_t)bh * 1024 + i] = aS[i];
    // WcT slice: thread (e = t&31, mg = t>>5) does 16 m values
    int e = t & 31, mg = t >> 5;
    float prow[32];
#pragma unroll
    for (int d = 0; d < 32; ++d) prow[d] = aS[d * 32 + e];
#pragma unroll 4
    for (int mi = 0; mi < 16; ++mi) {
        int ml = mg * 16 + mi;
        float acc = 0.f;
#pragma unroll
        for (int d = 0; d < 32; ++d)
            acc += prow[d] * wSf[d * 128 + ml];
        int m = mq * 128 + ml;
        WcT[((size_t)b * 512 + m) * 128 + h * 32 + e] = f2h(acc);
    }
}

// ---------------------------------------------------------------------------
// K3: fused output GEMM + LayerNorm.  Block = 64 rows x 512 cols (full rows).
// x = Vm @ Wc_b + Qm @ Wqo + (bo+bqo); y = LN(x)*gamma+beta -> d_out fp32.
// All-f16 operands (R0 2-barrier structure — the best-measured out_ln).
// ---------------------------------------------------------------------------
__global__ __launch_bounds__(256) void k_out_ln(
        const ushort* __restrict__ Vm, const ushort* __restrict__ Qm,
        const ushort* __restrict__ WcT, const ushort* __restrict__ WqoT,
        const float* __restrict__ bo, const float* __restrict__ bqo,
        const float* __restrict__ gamma, const float* __restrict__ beta,
        float* __restrict__ Y) {
    __shared__ __align__(16) ushort As[64 * LDSS];
    __shared__ __align__(16) ushort Bs[512 * LDSS];
    __shared__ float sumS[4][64], sumSS[4][64], muA[64], rsA[64];
    const int row0 = blockIdx.x * 64;
    const int b = row0 >> 12;
    const ushort* WcTb = WcT + (size_t)b * 512 * 128;
    const int tid = threadIdx.x;
    const int wid = tid >> 6, lane = tid & 63;
    const int quad = lane >> 4, l16 = lane & 15;
    const int sr = tid >> 2;            // 0..63
    const int sc = (tid & 3) * 8;       // 0,8,16,24

    f32x4 acc[4][8] = {};

    for (int k0 = 0; k0 < 256; k0 += 32) {
        const ushort* Asrc; const ushort* Bsrc; int kk;
        if (k0 < 128) { Asrc = Vm; Bsrc = WcTb; kk = k0; }
        else          { Asrc = Qm; Bsrc = WqoT; kk = k0 - 128; }
        __syncthreads();
        *(uint4*)&As[sr * LDSS + sc] =
            *(const uint4*)&Asrc[(size_t)(row0 + sr) * 128 + kk + sc];
#pragma unroll
        for (int p = 0; p < 8; ++p) {
            int r = sr + p * 64;
            *(uint4*)&Bs[r * LDSS + sc] = *(const uint4*)&Bsrc[(size_t)r * 128 + kk + sc];
        }
        __syncthreads();
        f16x8 aF[4];
#pragma unroll
        for (int i = 0; i < 4; ++i)
            aF[i] = *reinterpret_cast<const f16x8*>(&As[(i * 16 + l16) * LDSS + quad * 8]);
#pragma unroll
        for (int j = 0; j < 8; ++j) {
            f16x8 bF = *reinterpret_cast<const f16x8*>(
                &Bs[(wid * 128 + j * 16 + l16) * LDSS + quad * 8]);
#pragma unroll
            for (int i = 0; i < 4; ++i)
                acc[i][j] = __builtin_amdgcn_mfma_f32_16x16x32_f16(aF[i], bF, acc[i][j], 0, 0, 0);
        }
    }

    float bv[8];
#pragma unroll
    for (int j = 0; j < 8; ++j) {
        int ncol = wid * 128 + j * 16 + l16;
        bv[j] = bo[ncol] + bqo[ncol];
    }
    float sArr[4][4], ssArr[4][4];
#pragma unroll
    for (int i = 0; i < 4; ++i)
#pragma unroll
        for (int r = 0; r < 4; ++r) {
            float s = 0.f, ss = 0.f;
#pragma unroll
            for (int j = 0; j < 8; ++j) {
                float x = acc[i][j][r] + bv[j];
                s += x; ss += x * x;
            }
            sArr[i][r] = s; ssArr[i][r] = ss;
        }
#pragma unroll
    for (int off = 1; off < 16; off <<= 1)
#pragma unroll
        for (int i = 0; i < 4; ++i)
#pragma unroll
            for (int r = 0; r < 4; ++r) {
                sArr[i][r]  += __shfl_xor(sArr[i][r],  off, 64);
                ssArr[i][r] += __shfl_xor(ssArr[i][r], off, 64);
            }
    if (l16 == 0) {
#pragma unroll
        for (int i = 0; i < 4; ++i)
#pragma unroll
            for (int r = 0; r < 4; ++r) {
                int row = i * 16 + quad * 4 + r;
                sumS[wid][row]  = sArr[i][r];
                sumSS[wid][row] = ssArr[i][r];
            }
    }
    __syncthreads();
    if (tid < 64) {
        float s = sumS[0][tid] + sumS[1][tid] + sumS[2][tid] + sumS[3][tid];
        float ss = sumSS[0][tid] + sumSS[1][tid] + sumSS[2][tid] + sumSS[3][tid];
        float mu = s * (1.f / 512.f);
        float var = ss * (1.f / 512.f) - mu * mu;
        muA[tid] = mu;
        rsA[tid] = rsqrtf(var + 1e-5f);
    }
    __syncthreads();

    float gj[8], bj[8];
#pragma unroll
    for (int j = 0; j < 8; ++j) {
        int ncol = wid * 128 + j * 16 + l16;
        gj[j] = gamma[ncol]; bj[j] = beta[ncol];
    }
#pragma unroll
    for (int i = 0; i < 4; ++i)
#pragma unroll
        for (int r = 0; r < 4; ++r) {
            int row = i * 16 + quad * 4 + r;
            float mu = muA[row], rstd = rsA[row];
            size_t base = (size_t)(row0 + row) * 512 + wid * 128 + l16;
#pragma unroll
            for (int j = 0; j < 8; ++j) {
                float x = acc[i][j][r] + bv[j];
                Y[base + j * 16] = (x - mu) * rstd * gj[j] + bj[j];
            }
        }
}

// ---------------------------------------------------------------------------
extern "C" void kernel_launch(void* const* d_in, const int* in_sizes, int n_in,
                              void* d_out, int out_size, void* d_ws, size_t ws_size,
                              hipStream_t stream) {
    const float* Qin   = (const float*)d_in[0];
    const float* KVin  = (const float*)d_in[1];
    const float* Wq    = (const float*)d_in[2];
    const float* bq    = (const float*)d_in[3];
    const float* Wk    = (const float*)d_in[4];
    const float* bk    = (const float*)d_in[5];
    const float* Wv    = (const float*)d_in[6];
    const float* bv    = (const float*)d_in[7];
    const float* Wo    = (const float*)d_in[8];
    const float* bo    = (const float*)d_in[9];
    const float* Wqo   = (const float*)d_in[10];
    const float* bqo   = (const float*)d_in[11];
    const float* gamma = (const float*)d_in[12];
    const float* beta  = (const float*)d_in[13];
    float* out = (float*)d_out;           // [y (16*4096*512) | attn (16*4*32*32)]
    float* attnOut = out + 33554432;

    char* ws = (char*)d_ws;
    ushort* WqT  = (ushort*)(ws);                 // 131072
    ushort* WkT  = (ushort*)(ws + 131072);        // 131072
    ushort* WvT  = (ushort*)(ws + 262144);        // 131072
    ushort* WqoT = (ushort*)(ws + 393216);        // 131072 (f16)
    ushort* WoH  = (ushort*)(ws + 524288);        // 131072 (f16)
    ushort* QmH  = (ushort*)(ws + 655360);        // 16777216 (f16)
    ushort* VmH  = (ushort*)(ws + 17432576);      // 16777216 (f16)
    float*  part = (float*) (ws + 34209792);      // 8388608
    ushort* WcT  = (ushort*)(ws + 42598400);      // 2097152 (f16)
    // total ws use: 44,695,552 bytes

    k_prep<<<1280, 256, 0, stream>>>(Wq, Wk, Wv, Wqo, Wo,
                                     WqT, WkT, WvT, WqoT, WoH);
    k_qkv_scores<<<512, 256, 0, stream>>>(Qin, KVin, WqT, WkT, WvT,
                                          bq, bk, bv, QmH, VmH, part);
    k_attn<<<dim3(64, 4), 256, 0, stream>>>(part, WoH, attnOut, WcT);
    k_out_ln<<<1024, 256, 0, stream>>>(VmH, QmH, WcT, WqoT, bo, bqo, gamma, beta, out);
}